// Round 1
// baseline (78.473 us; speedup 1.0000x reference)
//
#include <hip/hip_runtime.h>

#define BATCH 16384
#define DIM   2048
#define NTASK 8
#define ODIM  128
#define NCTR  4
#define KMASK 256   /* DIM / NTASK  */
#define OCN   512   /* ODIM * NCTR  */

#define BM 64
#define BN 64
#define BK 32

__device__ __forceinline__ int task0_id(const float* __restrict__ task) {
    // task_input[0][0..7] is one-hot; find the hot index.
    int t0 = 0;
#pragma unroll
    for (int j = 1; j < NTASK; ++j) {
        if (task[j] > 0.5f) t0 = j;
    }
    return t0;
}

// w2[oc] = sum_k centers[oc, t0*256 + k]^2   (oc = o*4 + c, flat leading index)
__global__ void w2_kernel(const float* __restrict__ task,
                          const float* __restrict__ centers,
                          float* __restrict__ w2) {
    const int oc = blockIdx.x * blockDim.x + threadIdx.x;
    if (oc >= OCN) return;
    const int t0 = task0_id(task);
    const float4* p =
        reinterpret_cast<const float4*>(centers + (size_t)oc * DIM + t0 * KMASK);
    float s = 0.0f;
#pragma unroll 8
    for (int i = 0; i < KMASK / 4; ++i) {
        float4 v = p[i];
        s = fmaf(v.x, v.x, s);
        s = fmaf(v.y, v.y, s);
        s = fmaf(v.z, v.z, s);
        s = fmaf(v.w, v.w, s);
    }
    w2[oc] = s;
}

// x2[row] = sum_k x[row, t0*256 + k]^2  — one wave per row, float4/lane + butterfly
__global__ void x2_kernel(const float* __restrict__ task,
                          const float* __restrict__ x,
                          float* __restrict__ x2) {
    const int row  = blockIdx.x * 4 + (threadIdx.x >> 6);
    const int lane = threadIdx.x & 63;
    const int t0   = task0_id(task);
    float4 v = *reinterpret_cast<const float4*>(
        x + (size_t)row * DIM + t0 * KMASK + lane * 4);
    float s = v.x * v.x + v.y * v.y + v.z * v.z + v.w * v.w;
#pragma unroll
    for (int off = 32; off > 0; off >>= 1) s += __shfl_xor(s, off);
    if (lane == 0) x2[row] = s;
}

// Main: cross GEMM (M=BATCH, N=OCN, K=KMASK) + fused Gaussian epilogue.
__global__ __launch_bounds__(256)
void gauss_main_kernel(const float* __restrict__ task,
                       const float* __restrict__ x,
                       const float* __restrict__ centers,
                       const float* __restrict__ w2,
                       const float* __restrict__ x2,
                       float* __restrict__ out) {
    __shared__ float As[BK][BM];   // k-major: As[kk][m]
    __shared__ float Bs[BK][BN];   // k-major: Bs[kk][n]

    const int tid = threadIdx.x;
    const int bm  = blockIdx.x * BM;
    const int nb  = blockIdx.y * BN;
    const int t0  = task0_id(task);

    // 16 x 16 thread grid, 4x4 microtile. n0 is 4-aligned -> one o per thread.
    const int tm = tid & 15;
    const int tn = tid >> 4;
    const int m0 = tm * 4;
    const int n0 = tn * 4;

    // staging map: each thread loads 8 contiguous k's for one row/col
    const int lm = tid & 63;
    const int lk = (tid >> 6) * 8;

    const float* xb = x + (size_t)(bm + lm) * DIM + t0 * KMASK + lk;
    const float* cb = centers + (size_t)(nb + lm) * DIM + t0 * KMASK + lk;

    float acc[4][4] = {};

    for (int k0 = 0; k0 < KMASK; k0 += BK) {
        float4 a0 = *reinterpret_cast<const float4*>(xb + k0);
        float4 a1 = *reinterpret_cast<const float4*>(xb + k0 + 4);
        float4 b0 = *reinterpret_cast<const float4*>(cb + k0);
        float4 b1 = *reinterpret_cast<const float4*>(cb + k0 + 4);
        __syncthreads();   // previous iteration's readers are done
        As[lk + 0][lm] = a0.x; As[lk + 1][lm] = a0.y;
        As[lk + 2][lm] = a0.z; As[lk + 3][lm] = a0.w;
        As[lk + 4][lm] = a1.x; As[lk + 5][lm] = a1.y;
        As[lk + 6][lm] = a1.z; As[lk + 7][lm] = a1.w;
        Bs[lk + 0][lm] = b0.x; Bs[lk + 1][lm] = b0.y;
        Bs[lk + 2][lm] = b0.z; Bs[lk + 3][lm] = b0.w;
        Bs[lk + 4][lm] = b1.x; Bs[lk + 5][lm] = b1.y;
        Bs[lk + 6][lm] = b1.z; Bs[lk + 7][lm] = b1.w;
        __syncthreads();
#pragma unroll
        for (int kk = 0; kk < BK; ++kk) {
            float4 a = *reinterpret_cast<const float4*>(&As[kk][m0]);
            float4 b = *reinterpret_cast<const float4*>(&Bs[kk][n0]);
            float av[4] = {a.x, a.y, a.z, a.w};
            float bv[4] = {b.x, b.y, b.z, b.w};
#pragma unroll
            for (int i = 0; i < 4; ++i)
#pragma unroll
                for (int j = 0; j < 4; ++j)
                    acc[i][j] = fmaf(av[i], bv[j], acc[i][j]);
        }
    }

    // Epilogue: this thread's 4 n's are the 4 centers of one output unit o.
    const int oc0 = nb + n0;          // multiple of 4
    const int o   = oc0 >> 2;
    const float w2v0 = w2[oc0 + 0];
    const float w2v1 = w2[oc0 + 1];
    const float w2v2 = w2[oc0 + 2];
    const float w2v3 = w2[oc0 + 3];
    const int tcol = o >> 4;          // out_mask column = o / 16

#pragma unroll
    for (int i = 0; i < 4; ++i) {
        const int r = bm + m0 + i;
        const float x2r = x2[r];
        const float msk = task[r * NTASK + tcol];   // per-row mask (not row 0!)
        float g0 = __expf(-0.5f * (x2r + w2v0 - 2.0f * acc[i][0]));
        float g1 = __expf(-0.5f * (x2r + w2v1 - 2.0f * acc[i][1]));
        float g2 = __expf(-0.5f * (x2r + w2v2 - 2.0f * acc[i][2]));
        float g3 = __expf(-0.5f * (x2r + w2v3 - 2.0f * acc[i][3]));
        float S  = g0 + g1 + g2 + g3;
        float Mx = fmaxf(fmaxf(g0, g1), fmaxf(g2, g3));
        float P  = S / (S + 4.0f - 4.0f * Mx);
        out[(size_t)r * ODIM + o] = P * msk;
    }
}

extern "C" void kernel_launch(void* const* d_in, const int* in_sizes, int n_in,
                              void* d_out, int out_size, void* d_ws, size_t ws_size,
                              hipStream_t stream) {
    const float* task    = (const float*)d_in[0];   // [16384, 8]
    const float* x       = (const float*)d_in[1];   // [16384, 2048]
    const float* centers = (const float*)d_in[2];   // [128, 4, 2048]
    float* out = (float*)d_out;                     // [16384, 128]

    float* w2 = (float*)d_ws;        // 512 floats
    float* x2 = w2 + OCN;            // 16384 floats  (total ws use: ~66 KB)

    w2_kernel<<<dim3(2), dim3(256), 0, stream>>>(task, centers, w2);
    x2_kernel<<<dim3(BATCH / 4), dim3(256), 0, stream>>>(task, x, x2);

    dim3 grid(BATCH / BM, OCN / BN);
    gauss_main_kernel<<<grid, dim3(256), 0, stream>>>(task, x, centers, w2, x2, out);
}

// Round 2
// 32.965 us; speedup vs baseline: 2.3805x; 2.3805x over previous
//
#include <hip/hip_runtime.h>

typedef unsigned short u16;
typedef __attribute__((ext_vector_type(8))) short bf16x8;
typedef __attribute__((ext_vector_type(4))) float f32x4;

#define BATCH 16384
#define DIM   2048
#define NTASK 8
#define ODIM  128
#define KMASK 256   /* DIM / NTASK */
#define OCN   512   /* ODIM * 4    */
#define BM    64

__device__ __forceinline__ int task0_id(const float* __restrict__ t) {
    int t0 = 0;
#pragma unroll
    for (int j = 1; j < NTASK; ++j)
        if (t[j] > 0.5f) t0 = j;
    return t0;
}

// fp32 -> bf16 (round-nearest-even on the bit pattern; inputs are finite/normal)
__device__ __forceinline__ u16 f2bf(float f) {
    union { float f; unsigned u; } v; v.f = f;
    unsigned r = v.u + 0x7FFF + ((v.u >> 16) & 1);
    return (u16)(r >> 16);
}

// One wave per oc row: w2h[oc] = -0.5 * sum_k centers[oc, t0*256+k]^2,
// and convert the masked slice to bf16 (k-contiguous) into Bbf[oc][256].
__global__ __launch_bounds__(256)
void prep_kernel(const float* __restrict__ task,
                 const float* __restrict__ centers,
                 u16* __restrict__ Bbf,
                 float* __restrict__ w2h) {
    const int oc   = blockIdx.x * 4 + (threadIdx.x >> 6);
    const int lane = threadIdx.x & 63;
    const int t0   = task0_id(task);
    float4 v = *reinterpret_cast<const float4*>(
        centers + (size_t)oc * DIM + t0 * KMASK + lane * 4);
    float s = v.x * v.x + v.y * v.y + v.z * v.z + v.w * v.w;
#pragma unroll
    for (int off = 32; off; off >>= 1) s += __shfl_xor(s, off);
    if (lane == 0) w2h[oc] = -0.5f * s;
    ushort4 b;
    b.x = f2bf(v.x); b.y = f2bf(v.y); b.z = f2bf(v.z); b.w = f2bf(v.w);
    *reinterpret_cast<ushort4*>(Bbf + (size_t)oc * KMASK + lane * 4) = b;
}

// Main: A (x slice) staged to bf16 LDS (XOR-swizzled) + fused x2;
// MFMA 16x16x32 over K=256; fused Gaussian epilogue with 4-lane c-reduction.
__global__ __launch_bounds__(512)
void gauss_mfma_kernel(const float* __restrict__ task,
                       const float* __restrict__ x,
                       const u16* __restrict__ Bbf,
                       const float* __restrict__ w2h,
                       float* __restrict__ out) {
    __shared__ u16 As[BM * KMASK];      // 32 KB, 16B-slot XOR swizzle
    __shared__ float x2s[BM];           // -0.5 * row norms
    __shared__ float msks[BM][NTASK];   // per-row task mask

    const int tid = threadIdx.x;
    const int bm  = blockIdx.x * BM;
    const int t0  = task0_id(task);

    // ---- stage A + x2 ----
    {
        const int srow = tid >> 3;          // 0..63
        const int sc   = (tid & 7) * 32;    // col base, 32 cols/thread
        const float* xp = x + (size_t)(bm + srow) * DIM + t0 * KMASK + sc;
        float sq = 0.f;
#pragma unroll
        for (int c = 0; c < 4; ++c) {
            float4 v0 = *reinterpret_cast<const float4*>(xp + c * 8);
            float4 v1 = *reinterpret_cast<const float4*>(xp + c * 8 + 4);
            sq += v0.x * v0.x + v0.y * v0.y + v0.z * v0.z + v0.w * v0.w
                + v1.x * v1.x + v1.y * v1.y + v1.z * v1.z + v1.w * v1.w;
            unsigned p0 = (unsigned)f2bf(v0.x) | ((unsigned)f2bf(v0.y) << 16);
            unsigned p1 = (unsigned)f2bf(v0.z) | ((unsigned)f2bf(v0.w) << 16);
            unsigned p2 = (unsigned)f2bf(v1.x) | ((unsigned)f2bf(v1.y) << 16);
            unsigned p3 = (unsigned)f2bf(v1.z) | ((unsigned)f2bf(v1.w) << 16);
            const int slot = (sc >> 3) + c;              // 16B slot 0..31
            const int sw   = slot ^ (srow & 7);
            *reinterpret_cast<int4*>(&As[srow * KMASK + sw * 8]) =
                make_int4((int)p0, (int)p1, (int)p2, (int)p3);
        }
        sq += __shfl_xor(sq, 1);
        sq += __shfl_xor(sq, 2);
        sq += __shfl_xor(sq, 4);
        if ((tid & 7) == 0) x2s[srow] = -0.5f * sq;
        msks[tid >> 3][tid & 7] =
            task[(size_t)(bm + (tid >> 3)) * NTASK + (tid & 7)];
    }
    __syncthreads();

    const int wave = tid >> 6;     // 0..7, owns oc [wave*64, wave*64+64)
    const int lane = tid & 63;
    const int l15  = lane & 15;
    const int g    = lane >> 4;    // k-chunk group

    f32x4 acc[4][4];
#pragma unroll
    for (int mt = 0; mt < 4; ++mt)
#pragma unroll
        for (int nt = 0; nt < 4; ++nt)
            acc[mt][nt] = (f32x4){0.f, 0.f, 0.f, 0.f};

    const u16* bp = Bbf + (size_t)(wave * 64 + l15) * KMASK + g * 8;

#pragma unroll
    for (int ks = 0; ks < 8; ++ks) {
        bf16x8 av[4], bv[4];
#pragma unroll
        for (int mt = 0; mt < 4; ++mt) {
            const int row  = mt * 16 + l15;
            const int sw   = (ks * 4 + g) ^ (row & 7);
            av[mt] = *reinterpret_cast<const bf16x8*>(&As[row * KMASK + sw * 8]);
        }
#pragma unroll
        for (int nt = 0; nt < 4; ++nt)
            bv[nt] = *reinterpret_cast<const bf16x8*>(bp + nt * 16 * KMASK + ks * 32);
#pragma unroll
        for (int mt = 0; mt < 4; ++mt)
#pragma unroll
            for (int nt = 0; nt < 4; ++nt)
                acc[mt][nt] = __builtin_amdgcn_mfma_f32_16x16x32_bf16(
                    av[mt], bv[nt], acc[mt][nt], 0, 0, 0);
    }

    // ---- epilogue: G=exp(cross - x2/2 - w2/2); S,M over 4 centers; P; mask ----
    // D layout: col = lane&15 (oc), row = g*4 + reg. This wave's o's all map to
    // task column == wave.
#pragma unroll
    for (int nt = 0; nt < 4; ++nt) {
        const int oc   = wave * 64 + nt * 16 + l15;
        const float wv = w2h[oc];
        const int o    = oc >> 2;
#pragma unroll
        for (int mt = 0; mt < 4; ++mt) {
#pragma unroll
            for (int r = 0; r < 4; ++r) {
                const int row = mt * 16 + g * 4 + r;
                const float gg = __expf(acc[mt][nt][r] + x2s[row] + wv);
                float s = gg + __shfl_xor(gg, 1);
                s += __shfl_xor(s, 2);
                float mx = fmaxf(gg, __shfl_xor(gg, 1));
                mx = fmaxf(mx, __shfl_xor(mx, 2));
                const float P = s / (s + 4.0f - 4.0f * mx);
                if ((lane & 3) == 0)
                    out[(size_t)(bm + row) * ODIM + o] = P * msks[row][wave];
            }
        }
    }
}

extern "C" void kernel_launch(void* const* d_in, const int* in_sizes, int n_in,
                              void* d_out, int out_size, void* d_ws, size_t ws_size,
                              hipStream_t stream) {
    const float* task    = (const float*)d_in[0];   // [16384, 8]
    const float* x       = (const float*)d_in[1];   // [16384, 2048]
    const float* centers = (const float*)d_in[2];   // [128, 4, 2048]
    float* out = (float*)d_out;                     // [16384, 128]

    u16*   Bbf = (u16*)d_ws;                        // 512*256 bf16 = 256 KB
    float* w2h = (float*)((char*)d_ws + OCN * KMASK * sizeof(u16));  // 512 f32

    prep_kernel<<<dim3(OCN / 4), dim3(256), 0, stream>>>(task, centers, Bbf, w2h);
    gauss_mfma_kernel<<<dim3(BATCH / BM), dim3(512), 0, stream>>>(
        task, x, Bbf, w2h, out);
}

// Round 3
// 30.733 us; speedup vs baseline: 2.5533x; 1.0726x over previous
//
#include <hip/hip_runtime.h>

typedef unsigned short u16;
typedef __attribute__((ext_vector_type(8))) short bf16x8;
typedef __attribute__((ext_vector_type(4))) float f32x4;

#define BATCH 16384
#define DIM   2048
#define NTASK 8
#define ODIM  128
#define KMASK 256   /* DIM / NTASK */
#define OCN   512   /* ODIM * 4    */
#define BM    32

__device__ __forceinline__ int task0_id(const float* __restrict__ t) {
    int t0 = 0;
#pragma unroll
    for (int j = 1; j < NTASK; ++j)
        if (t[j] > 0.5f) t0 = j;
    return t0;
}

// fp32 -> bf16 round-nearest-even on bits (inputs finite)
__device__ __forceinline__ u16 f2bf(float f) {
    union { float f; unsigned u; } v; v.f = f;
    unsigned r = v.u + 0x7FFF + ((v.u >> 16) & 1);
    return (u16)(r >> 16);
}

// One wave per oc: compute -w2/2 and bf16-convert the masked slice, written
// C-MAJOR: row' = c*128 + o  (input row oc = o*4 + c).
__global__ __launch_bounds__(256)
void prep_kernel(const float* __restrict__ task,
                 const float* __restrict__ centers,
                 u16* __restrict__ Bbf,
                 float* __restrict__ w2c) {
    const int oc   = blockIdx.x * 4 + (threadIdx.x >> 6);
    const int lane = threadIdx.x & 63;
    const int t0   = task0_id(task);
    const int rowp = (oc & 3) * ODIM + (oc >> 2);   // c*128 + o
    float4 v = *reinterpret_cast<const float4*>(
        centers + (size_t)oc * DIM + t0 * KMASK + lane * 4);
    float s = v.x * v.x + v.y * v.y + v.z * v.z + v.w * v.w;
#pragma unroll
    for (int off = 32; off; off >>= 1) s += __shfl_xor(s, off);
    if (lane == 0) w2c[rowp] = -0.5f * s;
    ushort4 b;
    b.x = f2bf(v.x); b.y = f2bf(v.y); b.z = f2bf(v.z); b.w = f2bf(v.w);
    *reinterpret_cast<ushort4*>(Bbf + (size_t)rowp * KMASK + lane * 4) = b;
}

// Main: BM=32 rows/block, 4 waves; wave owns 32 o's (all 4 centers in-lane).
__global__ __launch_bounds__(256)
void gauss_mfma_kernel(const float* __restrict__ task,
                       const float* __restrict__ x,
                       const u16* __restrict__ Bbf,
                       const float* __restrict__ w2c,
                       float* __restrict__ out) {
    __shared__ u16 As[BM * KMASK];      // 16 KB, 16B-slot XOR swizzle
    __shared__ float x2s[BM];           // -0.5 * masked row norms
    __shared__ float msks[BM][NTASK];

    const int tid = threadIdx.x;
    const int bm  = blockIdx.x * BM;
    const int t0  = task0_id(task);

    // ---- stage A (fp32 -> bf16 LDS) + fused x2 ----
    {
        const int srow = tid >> 3;          // 0..31
        const int sc   = (tid & 7) * 32;    // 32 cols per thread
        const float* xp = x + (size_t)(bm + srow) * DIM + t0 * KMASK + sc;
        float sq = 0.f;
#pragma unroll
        for (int c = 0; c < 4; ++c) {
            float4 v0 = *reinterpret_cast<const float4*>(xp + c * 8);
            float4 v1 = *reinterpret_cast<const float4*>(xp + c * 8 + 4);
            sq += v0.x * v0.x + v0.y * v0.y + v0.z * v0.z + v0.w * v0.w
                + v1.x * v1.x + v1.y * v1.y + v1.z * v1.z + v1.w * v1.w;
            unsigned p0 = (unsigned)f2bf(v0.x) | ((unsigned)f2bf(v0.y) << 16);
            unsigned p1 = (unsigned)f2bf(v0.z) | ((unsigned)f2bf(v0.w) << 16);
            unsigned p2 = (unsigned)f2bf(v1.x) | ((unsigned)f2bf(v1.y) << 16);
            unsigned p3 = (unsigned)f2bf(v1.z) | ((unsigned)f2bf(v1.w) << 16);
            const int slot = (sc >> 3) + c;
            const int sw   = slot ^ (srow & 7);
            *reinterpret_cast<int4*>(&As[srow * KMASK + sw * 8]) =
                make_int4((int)p0, (int)p1, (int)p2, (int)p3);
        }
        sq += __shfl_xor(sq, 1);
        sq += __shfl_xor(sq, 2);
        sq += __shfl_xor(sq, 4);
        if ((tid & 7) == 0) x2s[srow] = -0.5f * sq;
        msks[tid >> 3][tid & 7] =
            task[(size_t)(bm + (tid >> 3)) * NTASK + (tid & 7)];
    }
    __syncthreads();

    const int wave = tid >> 6;     // 0..3; owns o in [wave*32, wave*32+32)
    const int lane = tid & 63;
    const int l15  = lane & 15;
    const int g    = lane >> 4;

    f32x4 acc[2][2][4];            // [mt][no][c]
#pragma unroll
    for (int mt = 0; mt < 2; ++mt)
#pragma unroll
        for (int no = 0; no < 2; ++no)
#pragma unroll
            for (int c = 0; c < 4; ++c)
                acc[mt][no][c] = (f32x4){0.f, 0.f, 0.f, 0.f};

    // B row for (no,c): c*128 + wave*32 + no*16 + l15
    const u16* bp = Bbf + (size_t)(wave * 32 + l15) * KMASK + g * 8;

#pragma unroll
    for (int ks = 0; ks < 8; ++ks) {
        bf16x8 av[2];
#pragma unroll
        for (int mt = 0; mt < 2; ++mt) {
            const int row = mt * 16 + l15;
            const int sw  = (ks * 4 + g) ^ (row & 7);
            av[mt] = *reinterpret_cast<const bf16x8*>(&As[row * KMASK + sw * 8]);
        }
        bf16x8 bv[2][4];
#pragma unroll
        for (int no = 0; no < 2; ++no)
#pragma unroll
            for (int c = 0; c < 4; ++c)
                bv[no][c] = *reinterpret_cast<const bf16x8*>(
                    bp + ((size_t)(no * 16 + c * ODIM)) * KMASK + ks * 32);
#pragma unroll
        for (int mt = 0; mt < 2; ++mt)
#pragma unroll
            for (int no = 0; no < 2; ++no)
#pragma unroll
                for (int c = 0; c < 4; ++c)
                    acc[mt][no][c] = __builtin_amdgcn_mfma_f32_16x16x32_bf16(
                        av[mt], bv[no][c], acc[mt][no][c], 0, 0, 0);
    }

    // ---- epilogue: all in-lane; D layout col=l15, row=g*4+reg ----
    float w2v[2][4];
#pragma unroll
    for (int no = 0; no < 2; ++no)
#pragma unroll
        for (int c = 0; c < 4; ++c)
            w2v[no][c] = w2c[c * ODIM + wave * 32 + no * 16 + l15];

#pragma unroll
    for (int mt = 0; mt < 2; ++mt) {
#pragma unroll
        for (int r = 0; r < 4; ++r) {
            const int row = mt * 16 + g * 4 + r;
            const float xh = x2s[row];
#pragma unroll
            for (int no = 0; no < 2; ++no) {
                const float g0 = __expf(acc[mt][no][0][r] + xh + w2v[no][0]);
                const float g1 = __expf(acc[mt][no][1][r] + xh + w2v[no][1]);
                const float g2 = __expf(acc[mt][no][2][r] + xh + w2v[no][2]);
                const float g3 = __expf(acc[mt][no][3][r] + xh + w2v[no][3]);
                const float S  = g0 + g1 + g2 + g3;
                const float Mx = fmaxf(fmaxf(g0, g1), fmaxf(g2, g3));
                const float P  = S / (S + 4.0f - 4.0f * Mx);
                const float mk = msks[row][wave * 2 + no];
                out[(size_t)(bm + row) * ODIM + wave * 32 + no * 16 + l15] = P * mk;
            }
        }
    }
}

extern "C" void kernel_launch(void* const* d_in, const int* in_sizes, int n_in,
                              void* d_out, int out_size, void* d_ws, size_t ws_size,
                              hipStream_t stream) {
    const float* task    = (const float*)d_in[0];   // [16384, 8]
    const float* x       = (const float*)d_in[1];   // [16384, 2048]
    const float* centers = (const float*)d_in[2];   // [128, 4, 2048]
    float* out = (float*)d_out;                     // [16384, 128]

    u16*   Bbf = (u16*)d_ws;                        // 512*256 bf16 = 256 KB (c-major)
    float* w2c = (float*)((char*)d_ws + OCN * KMASK * sizeof(u16));  // 512 f32

    prep_kernel<<<dim3(OCN / 4), dim3(256), 0, stream>>>(task, centers, Bbf, w2c);
    gauss_mfma_kernel<<<dim3(BATCH / BM), dim3(256), 0, stream>>>(
        task, x, Bbf, w2c, out);
}